// Round 4
// baseline (337.422 us; speedup 1.0000x reference)
//
#include <hip/hip_runtime.h>
#include <stdint.h>

typedef unsigned short u16;
typedef unsigned int u32;
typedef __attribute__((ext_vector_type(8))) short short8;
typedef __attribute__((ext_vector_type(4))) float f32x4;
typedef __attribute__((ext_vector_type(4))) u16 u16x4;

#define DEV static __device__ __forceinline__

DEV void gload_lds16(const void* g, void* l) {
  __builtin_amdgcn_global_load_lds((const __attribute__((address_space(1))) void*)g,
                                   (__attribute__((address_space(3))) void*)l, 16, 0, 0);
}
DEV u16 f2bf(float x) {
  u32 u = __builtin_bit_cast(u32, x);
  return (u16)((u + 0x7fffu + ((u >> 16) & 1u)) >> 16);
}
DEV f32x4 mfma_bf16(short8 a, short8 b, f32x4 c) {
  return __builtin_amdgcn_mfma_f32_16x16x32_bf16(a, b, c, 0, 0, 0);
}

// ---------------------------------------------------------------------------
// f32 -> bf16 (RNE) conversion pre-pass over three concatenated arrays.
// ---------------------------------------------------------------------------
__global__ __launch_bounds__(256) void cvt3(
    const float* __restrict__ s0, u16* __restrict__ d0, int n0,
    const float* __restrict__ s1, u16* __restrict__ d1, int n1,
    const float* __restrict__ s2, u16* __restrict__ d2, int n2) {
  long i = (long)(blockIdx.x * 256 + threadIdx.x) * 4;
  const float* s; u16* d; long off;
  if (i < n0) { s = s0; d = d0; off = i; }
  else if (i < (long)n0 + n1) { s = s1; d = d1; off = i - n0; }
  else if (i < (long)n0 + n1 + n2) { s = s2; d = d2; off = i - n0 - n1; }
  else return;
  float4 v = *(const float4*)(s + off);
  u16x4 o; o.x = f2bf(v.x); o.y = f2bf(v.y); o.z = f2bf(v.z); o.w = f2bf(v.w);
  *(u16x4*)(d + off) = o;
}

// ---------------------------------------------------------------------------
// NT GEMM: C[m,n] = sum_k A[m,k]*B[n,k] + bias[n].  M=8192, K=1024.
// A,B bf16 (pre-converted); bias f32.
// MODE 0: scatter epilogue -> Q/K/V [b,h,t,d] bf16 (N=3072)
// MODE 1: plain epilogue -> Of [M,N] f32 (N=1024)
// LDS tiles [128][32] bf16, 16B-chunk XOR swizzle (chunk ^ ((row>>1)&3))
// applied on the *global source* side (global_load_lds writes linearly),
// same involution applied on the read side (rule #21).
// ---------------------------------------------------------------------------
template <int MODE>
__global__ __launch_bounds__(256, 2) void gemm_nt(
    const u16* __restrict__ A, const u16* __restrict__ Bw,
    const float* __restrict__ bias, u16* __restrict__ O0, u16* __restrict__ O1,
    u16* __restrict__ O2, float* __restrict__ Of, int N, int K) {
  __shared__ __align__(16) u16 At[128 * 32];
  __shared__ __align__(16) u16 Bt[128 * 32];
  const int tid = threadIdx.x, w = tid >> 6, l = tid & 63;
  const int lr = l & 15, lg = l >> 4;
  const int m0 = blockIdx.y * 128, n0 = blockIdx.x * 128;
  const int wm = w >> 1, wn = w & 1;

  f32x4 acc[4][4];
#pragma unroll
  for (int i = 0; i < 4; i++)
#pragma unroll
    for (int j = 0; j < 4; j++) acc[i][j] = (f32x4){0.f, 0.f, 0.f, 0.f};

  for (int k0 = 0; k0 < K; k0 += 32) {
#pragma unroll
    for (int i = 0; i < 4; i++) {
      int seg = i * 4 + w;          // 0..15 ; <8 -> A, >=8 -> B
      int segl = seg & 7;
      int c = segl * 64 + l;        // 16B chunk 0..511
      int row = c >> 2, cpos = c & 3;
      int cdat = cpos ^ ((row >> 1) & 3);
      const u16* src = (seg < 8 ? A + (size_t)(m0 + row) * K
                                : Bw + (size_t)(n0 + row) * K) + (k0 + cdat * 8);
      u16* dst = (seg < 8 ? At : Bt) + segl * 512;
      gload_lds16(src, dst);
    }
    __syncthreads();

    short8 af[4], bf[4];
#pragma unroll
    for (int mi = 0; mi < 4; mi++) {
      int row = wm * 64 + mi * 16 + lr;
      int cp = lg ^ ((row >> 1) & 3);
      af[mi] = *(const short8*)&At[row * 32 + cp * 8];
    }
#pragma unroll
    for (int ni = 0; ni < 4; ni++) {
      int row = wn * 64 + ni * 16 + lr;
      int cp = lg ^ ((row >> 1) & 3);
      bf[ni] = *(const short8*)&Bt[row * 32 + cp * 8];
    }
#pragma unroll
    for (int mi = 0; mi < 4; mi++)
#pragma unroll
      for (int ni = 0; ni < 4; ni++)
        acc[mi][ni] = mfma_bf16(af[mi], bf[ni], acc[mi][ni]);
    __syncthreads();
  }

  // epilogue: C row = m0+wm*64+mi*16+lg*4+r, col = n0+wn*64+ni*16+lr
#pragma unroll
  for (int ni = 0; ni < 4; ni++) {
    int gn = n0 + wn * 64 + ni * 16 + lr;
    float bs = bias[gn];
#pragma unroll
    for (int mi = 0; mi < 4; mi++) {
#pragma unroll
      for (int r = 0; r < 4; r++) {
        int gm = m0 + wm * 64 + mi * 16 + lg * 4 + r;
        float val = acc[mi][ni][r] + bs;
        if (MODE == 0) {
          int which = gn >> 10, hd = gn & 1023;
          int h = hd >> 6, d = hd & 63;
          int b = gm >> 11, t = gm & 2047;
          u16* dst = which == 0 ? O0 : (which == 1 ? O1 : O2);
          dst[((size_t)(b * 16 + h) * 2048 + t) * 64 + d] = f2bf(val);
        } else {
          Of[(size_t)gm * N + gn] = val;
        }
      }
    }
  }
}

// ---------------------------------------------------------------------------
// Flash attention fwd — asm-free baseline (unchanged from R3).
// Q,K,V in [bh][2048][64] bf16. One block = one bh x 128 Q rows; 4 waves x
// 32 rows; KV tile 64.
// ---------------------------------------------------------------------------
__global__ __launch_bounds__(256, 2) void attn_fwd(
    const u16* __restrict__ Q, const u16* __restrict__ Kg,
    const u16* __restrict__ Vg, u16* __restrict__ AO) {
  __shared__ __align__(16) u16 Kt[64 * 64];   // row-major, chunk^(row&7) swizzle
  __shared__ __align__(16) u16 VT[64][72];    // V transposed: [d][t], +8 pad
  __shared__ __align__(16) u16 Pl[4][32][72]; // per-wave P [q][k], +8 pad
  const int tid = threadIdx.x, w = tid >> 6, l = tid & 63;
  const int lr = l & 15, lg = l >> 4;
  const int bh = blockIdx.y;
  const int q0 = blockIdx.x * 128;
  const size_t base = (size_t)bh * 2048 * 64;
  const u16* Qb = Q + base;
  const u16* Kb = Kg + base;
  const u16* Vb = Vg + base;

  short8 qf[2][2];
#pragma unroll
  for (int qi = 0; qi < 2; qi++)
#pragma unroll
    for (int kk = 0; kk < 2; kk++)
      qf[qi][kk] = *(const short8*)&Qb[(size_t)(q0 + w * 32 + qi * 16 + lr) * 64 +
                                       kk * 32 + lg * 8];

  f32x4 oacc[2][4];
  float mrun[2][4], lrun[2][4];
#pragma unroll
  for (int qi = 0; qi < 2; qi++)
#pragma unroll
    for (int dj = 0; dj < 4; dj++) oacc[qi][dj] = (f32x4){0.f, 0.f, 0.f, 0.f};
#pragma unroll
  for (int qi = 0; qi < 2; qi++)
#pragma unroll
    for (int r = 0; r < 4; r++) { mrun[qi][r] = -3.0e38f; lrun[qi][r] = 0.f; }

  for (int kt = 0; kt < 32; kt++) {
    const int t0 = kt * 64;
    // ---- stage K via global_load_lds (source-swizzled, linear LDS dest) ----
#pragma unroll
    for (int i = 0; i < 2; i++) {
      int seg = i * 4 + w;           // 0..7
      int c = seg * 64 + l;          // 16B chunk 0..511
      int row = c >> 3, cpos = c & 7, cdat = cpos ^ (row & 7);
      gload_lds16(Kb + (size_t)(t0 + row) * 64 + cdat * 8, (u16*)Kt + seg * 512);
    }
    // ---- stage V transposed: wave w covers d rows w*16..w*16+15 ----
    {
      const u16* vsrc = &Vb[(size_t)(t0 + l) * 64 + w * 16];
      short8 v0 = *(const short8*)vsrc;
      short8 v1 = *(const short8*)(vsrc + 8);
#pragma unroll
      for (int e = 0; e < 8; e++) VT[w * 16 + e][l] = (u16)v0[e];
#pragma unroll
      for (int e = 0; e < 8; e++) VT[w * 16 + 8 + e][l] = (u16)v1[e];
    }
    __syncthreads();

    // ---- S = Q K^T ----
    f32x4 s[2][4];
#pragma unroll
    for (int kj = 0; kj < 4; kj++) {
      int row = kj * 16 + lr;
      const short8 kf0 = *(const short8*)&Kt[row * 64 + ((lg) ^ (row & 7)) * 8];
      const short8 kf1 = *(const short8*)&Kt[row * 64 + ((4 + lg) ^ (row & 7)) * 8];
#pragma unroll
      for (int qi = 0; qi < 2; qi++) {
        f32x4 z = (f32x4){0.f, 0.f, 0.f, 0.f};
        z = mfma_bf16(qf[qi][0], kf0, z);
        z = mfma_bf16(qf[qi][1], kf1, z);
        s[qi][kj] = z;
      }
    }

    // ---- online softmax (rows q = lg*4+r; cols lr within kj tiles) ----
    float ml[2][4], esc[2][4];
#pragma unroll
    for (int qi = 0; qi < 2; qi++)
#pragma unroll
      for (int r = 0; r < 4; r++) {
        float mx = fmaxf(fmaxf(s[qi][0][r], s[qi][1][r]),
                         fmaxf(s[qi][2][r], s[qi][3][r]));
        mx = fmaxf(mx, __shfl_xor(mx, 1));
        mx = fmaxf(mx, __shfl_xor(mx, 2));
        mx = fmaxf(mx, __shfl_xor(mx, 4));
        mx = fmaxf(mx, __shfl_xor(mx, 8));
        float mn = fmaxf(mrun[qi][r], mx);
        ml[qi][r] = mn;
        esc[qi][r] = __expf((mrun[qi][r] - mn) * 0.125f);
        mrun[qi][r] = mn;
      }
#pragma unroll
    for (int qi = 0; qi < 2; qi++)
#pragma unroll
      for (int kj = 0; kj < 4; kj++)
#pragma unroll
        for (int r = 0; r < 4; r++)
          s[qi][kj][r] = __expf((s[qi][kj][r] - ml[qi][r]) * 0.125f);
#pragma unroll
    for (int qi = 0; qi < 2; qi++)
#pragma unroll
      for (int r = 0; r < 4; r++) {
        float sm = s[qi][0][r] + s[qi][1][r] + s[qi][2][r] + s[qi][3][r];
        sm += __shfl_xor(sm, 1);
        sm += __shfl_xor(sm, 2);
        sm += __shfl_xor(sm, 4);
        sm += __shfl_xor(sm, 8);
        lrun[qi][r] = lrun[qi][r] * esc[qi][r] + sm;
#pragma unroll
        for (int dj = 0; dj < 4; dj++) oacc[qi][dj][r] *= esc[qi][r];
      }

    // ---- P -> per-wave LDS [q][k] ----
#pragma unroll
    for (int qi = 0; qi < 2; qi++)
#pragma unroll
      for (int kj = 0; kj < 4; kj++)
#pragma unroll
        for (int r = 0; r < 4; r++)
          Pl[w][qi * 16 + lg * 4 + r][kj * 16 + lr] = f2bf(s[qi][kj][r]);

    // ---- O += P V ----
#pragma unroll
    for (int kk = 0; kk < 2; kk++) {
      short8 pa[2], vb[4];
#pragma unroll
      for (int qi = 0; qi < 2; qi++)
        pa[qi] = *(const short8*)&Pl[w][qi * 16 + lr][kk * 32 + lg * 8];
#pragma unroll
      for (int dj = 0; dj < 4; dj++)
        vb[dj] = *(const short8*)&VT[dj * 16 + lr][kk * 32 + lg * 8];
#pragma unroll
      for (int qi = 0; qi < 2; qi++)
#pragma unroll
        for (int dj = 0; dj < 4; dj++)
          oacc[qi][dj] = mfma_bf16(pa[qi], vb[dj], oacc[qi][dj]);
    }
    __syncthreads();
  }

  // ---- normalize and write AO [b][t][h*64+d] bf16 ----
  const int b = bh >> 4, h = bh & 15;
#pragma unroll
  for (int qi = 0; qi < 2; qi++) {
    float inv[4];
#pragma unroll
    for (int r = 0; r < 4; r++) inv[r] = 1.0f / lrun[qi][r];
#pragma unroll
    for (int dj = 0; dj < 4; dj++)
#pragma unroll
      for (int r = 0; r < 4; r++) {
        int t = q0 + w * 32 + qi * 16 + lg * 4 + r;
        AO[((size_t)(b * 2048 + t)) * 1024 + h * 64 + dj * 16 + lr] =
            f2bf(oacc[qi][dj][r] * inv[r]);
      }
  }
}

extern "C" void kernel_launch(void* const* d_in, const int* in_sizes, int n_in,
                              void* d_out, int out_size, void* d_ws,
                              size_t ws_size, hipStream_t stream) {
  const float* x    = (const float*)d_in[0];  // [4,2048,1024] f32
  const float* Wqkv = (const float*)d_in[1];  // [3072,1024] f32
  const float* bqkv = (const float*)d_in[2];  // [3072] f32
  const float* Wout = (const float*)d_in[3];  // [1024,1024] f32
  const float* bout = (const float*)d_in[4];  // [1024] f32
  float* out = (float*)d_out;                 // [4,2048,1024] f32

  // workspace (u16 units): q,k,v [64][2048][64]; xb [8192][1024] (reused as ao);
  // wqkvb [3072][1024]; woutb [1024][1024].  Total 75.5 MB.
  u16* q     = (u16*)d_ws;
  u16* k     = q + (size_t)8388608;
  u16* v     = k + (size_t)8388608;
  u16* xb    = v + (size_t)8388608;
  u16* ao    = xb;  // alias: xb dead after gemm<0>
  u16* wqkvb = xb + (size_t)8388608;
  u16* woutb = wqkvb + (size_t)3145728;

  cvt3<<<12288, 256, 0, stream>>>(x, xb, 8388608, Wqkv, wqkvb, 3145728,
                                  Wout, woutb, 1048576);
  gemm_nt<0><<<dim3(24, 64), 256, 0, stream>>>(xb, wqkvb, bqkv, q, k, v,
                                               nullptr, 3072, 1024);
  attn_fwd<<<dim3(16, 64), 256, 0, stream>>>(q, k, v, ao);
  gemm_nt<1><<<dim3(8, 64), 256, 0, stream>>>(ao, woutb, bout, nullptr, nullptr,
                                              nullptr, out, 1024, 1024);
}

// Round 5
// 313.965 us; speedup vs baseline: 1.0747x; 1.0747x over previous
//
#include <hip/hip_runtime.h>
#include <stdint.h>

typedef unsigned short u16;
typedef unsigned int u32;
typedef __attribute__((ext_vector_type(8))) short short8;
typedef __attribute__((ext_vector_type(4))) float f32x4;
typedef __attribute__((ext_vector_type(4))) u16 u16x4;

#define DEV static __device__ __forceinline__

DEV void gload_lds16(const void* g, void* l) {
  __builtin_amdgcn_global_load_lds((const __attribute__((address_space(1))) void*)g,
                                   (__attribute__((address_space(3))) void*)l, 16, 0, 0);
}
DEV u16 f2bf(float x) {
  u32 u = __builtin_bit_cast(u32, x);
  return (u16)((u + 0x7fffu + ((u >> 16) & 1u)) >> 16);
}
DEV f32x4 mfma_bf16(short8 a, short8 b, f32x4 c) {
  return __builtin_amdgcn_mfma_f32_16x16x32_bf16(a, b, c, 0, 0, 0);
}

// ---------------------------------------------------------------------------
// f32 -> bf16 (RNE) conversion pre-pass over three concatenated arrays.
// ---------------------------------------------------------------------------
__global__ __launch_bounds__(256) void cvt3(
    const float* __restrict__ s0, u16* __restrict__ d0, int n0,
    const float* __restrict__ s1, u16* __restrict__ d1, int n1,
    const float* __restrict__ s2, u16* __restrict__ d2, int n2) {
  long i = (long)(blockIdx.x * 256 + threadIdx.x) * 4;
  const float* s; u16* d; long off;
  if (i < n0) { s = s0; d = d0; off = i; }
  else if (i < (long)n0 + n1) { s = s1; d = d1; off = i - n0; }
  else if (i < (long)n0 + n1 + n2) { s = s2; d = d2; off = i - n0 - n1; }
  else return;
  float4 v = *(const float4*)(s + off);
  u16x4 o; o.x = f2bf(v.x); o.y = f2bf(v.y); o.z = f2bf(v.z); o.w = f2bf(v.w);
  *(u16x4*)(d + off) = o;
}

// ---------------------------------------------------------------------------
// NT GEMM (unchanged from R4-passing): C = A·B^T + bias. M=8192, K=1024.
// ---------------------------------------------------------------------------
template <int MODE>
__global__ __launch_bounds__(256, 2) void gemm_nt(
    const u16* __restrict__ A, const u16* __restrict__ Bw,
    const float* __restrict__ bias, u16* __restrict__ O0, u16* __restrict__ O1,
    u16* __restrict__ O2, float* __restrict__ Of, int N, int K) {
  __shared__ __align__(16) u16 At[128 * 32];
  __shared__ __align__(16) u16 Bt[128 * 32];
  const int tid = threadIdx.x, w = tid >> 6, l = tid & 63;
  const int lr = l & 15, lg = l >> 4;
  const int m0 = blockIdx.y * 128, n0 = blockIdx.x * 128;
  const int wm = w >> 1, wn = w & 1;

  f32x4 acc[4][4];
#pragma unroll
  for (int i = 0; i < 4; i++)
#pragma unroll
    for (int j = 0; j < 4; j++) acc[i][j] = (f32x4){0.f, 0.f, 0.f, 0.f};

  for (int k0 = 0; k0 < K; k0 += 32) {
#pragma unroll
    for (int i = 0; i < 4; i++) {
      int seg = i * 4 + w;          // 0..15 ; <8 -> A, >=8 -> B
      int segl = seg & 7;
      int c = segl * 64 + l;        // 16B chunk 0..511
      int row = c >> 2, cpos = c & 3;
      int cdat = cpos ^ ((row >> 1) & 3);
      const u16* src = (seg < 8 ? A + (size_t)(m0 + row) * K
                                : Bw + (size_t)(n0 + row) * K) + (k0 + cdat * 8);
      u16* dst = (seg < 8 ? At : Bt) + segl * 512;
      gload_lds16(src, dst);
    }
    __syncthreads();

    short8 af[4], bf[4];
#pragma unroll
    for (int mi = 0; mi < 4; mi++) {
      int row = wm * 64 + mi * 16 + lr;
      int cp = lg ^ ((row >> 1) & 3);
      af[mi] = *(const short8*)&At[row * 32 + cp * 8];
    }
#pragma unroll
    for (int ni = 0; ni < 4; ni++) {
      int row = wn * 64 + ni * 16 + lr;
      int cp = lg ^ ((row >> 1) & 3);
      bf[ni] = *(const short8*)&Bt[row * 32 + cp * 8];
    }
#pragma unroll
    for (int mi = 0; mi < 4; mi++)
#pragma unroll
      for (int ni = 0; ni < 4; ni++)
        acc[mi][ni] = mfma_bf16(af[mi], bf[ni], acc[mi][ni]);
    __syncthreads();
  }

#pragma unroll
  for (int ni = 0; ni < 4; ni++) {
    int gn = n0 + wn * 64 + ni * 16 + lr;
    float bs = bias[gn];
#pragma unroll
    for (int mi = 0; mi < 4; mi++) {
#pragma unroll
      for (int r = 0; r < 4; r++) {
        int gm = m0 + wm * 64 + mi * 16 + lg * 4 + r;
        float val = acc[mi][ni][r] + bs;
        if (MODE == 0) {
          int which = gn >> 10, hd = gn & 1023;
          int h = hd >> 6, d = hd & 63;
          int b = gm >> 11, t = gm & 2047;
          u16* dst = which == 0 ? O0 : (which == 1 ? O1 : O2);
          dst[((size_t)(b * 16 + h) * 2048 + t) * 64 + d] = f2bf(val);
        } else {
          Of[(size_t)gm * N + gn] = val;
        }
      }
    }
  }
}

// ---------------------------------------------------------------------------
// Flash attention fwd — R5: double-buffered K/V staging with prefetch
// (T14 issue-early/write-late), ONE barrier per KV-tile, setprio around MFMA.
// Same fragment layouts / softmax / P round-trip as the R4-passing version.
// ---------------------------------------------------------------------------
__global__ __launch_bounds__(256, 2) void attn_fwd(
    const u16* __restrict__ Q, const u16* __restrict__ Kg,
    const u16* __restrict__ Vg, u16* __restrict__ AO) {
  __shared__ __align__(16) u16 Kt[2][64 * 64];  // row-major, chunk^(row&7) swizzle
  __shared__ __align__(16) u16 VT[2][64][72];   // V transposed [d][t], +8 pad
  __shared__ __align__(16) u16 Pl[4][32][72];   // per-wave P [q][k], +8 pad
  const int tid = threadIdx.x, w = tid >> 6, l = tid & 63;
  const int lr = l & 15, lg = l >> 4;
  const int bh = blockIdx.y;
  const int q0 = blockIdx.x * 128;
  const size_t base = (size_t)bh * 2048 * 64;
  const u16* Qb = Q + base;
  const u16* Kb = Kg + base;
  const u16* Vb = Vg + base;

  // K-staging source indices (swizzled) for this thread
  const int kseg0 = w, kseg1 = 4 + w;

  short8 qf[2][2];
#pragma unroll
  for (int qi = 0; qi < 2; qi++)
#pragma unroll
    for (int kk = 0; kk < 2; kk++)
      qf[qi][kk] = *(const short8*)&Qb[(size_t)(q0 + w * 32 + qi * 16 + lr) * 64 +
                                       kk * 32 + lg * 8];

  f32x4 oacc[2][4];
  float mrun[2][4], lrun[2][4];
#pragma unroll
  for (int qi = 0; qi < 2; qi++)
#pragma unroll
    for (int dj = 0; dj < 4; dj++) oacc[qi][dj] = (f32x4){0.f, 0.f, 0.f, 0.f};
#pragma unroll
  for (int qi = 0; qi < 2; qi++)
#pragma unroll
    for (int r = 0; r < 4; r++) { mrun[qi][r] = -3.0e38f; lrun[qi][r] = 0.f; }

  // ---- prologue: stage tile 0 into buffer 0 ----
  {
#pragma unroll
    for (int i = 0; i < 2; i++) {
      int seg = i * 4 + w;
      int c = seg * 64 + l;
      int row = c >> 3, cpos = c & 7, cdat = cpos ^ (row & 7);
      gload_lds16(Kb + (size_t)row * 64 + cdat * 8, (u16*)&Kt[0][0] + seg * 512);
    }
    const u16* vsrc = &Vb[(size_t)l * 64 + w * 16];
    short8 v0 = *(const short8*)vsrc;
    short8 v1 = *(const short8*)(vsrc + 8);
#pragma unroll
    for (int e = 0; e < 8; e++) VT[0][w * 16 + e][l] = (u16)v0[e];
#pragma unroll
    for (int e = 0; e < 8; e++) VT[0][w * 16 + 8 + e][l] = (u16)v1[e];
  }
  __syncthreads();

  for (int kt = 0; kt < 32; kt++) {
    const int cur = kt & 1, nxt = cur ^ 1;
    short8 vr0, vr1;
    const bool pf = (kt < 31);
    if (pf) {
      const int t1 = (kt + 1) * 64;
      // issue K prefetch direct-to-LDS (inactive buffer)
#pragma unroll
      for (int i = 0; i < 2; i++) {
        int seg = i * 4 + w;
        int c = seg * 64 + l;
        int row = c >> 3, cpos = c & 7, cdat = cpos ^ (row & 7);
        gload_lds16(Kb + (size_t)(t1 + row) * 64 + cdat * 8,
                    (u16*)&Kt[nxt][0] + seg * 512);
      }
      // issue V prefetch to registers (written to LDS after softmax)
      const u16* vsrc = &Vb[(size_t)(t1 + l) * 64 + w * 16];
      vr0 = *(const short8*)vsrc;
      vr1 = *(const short8*)(vsrc + 8);
    }

    // ---- S = Q K^T from Kt[cur] ----
    f32x4 s[2][4];
    __builtin_amdgcn_s_setprio(1);
#pragma unroll
    for (int kj = 0; kj < 4; kj++) {
      int row = kj * 16 + lr;
      const short8 kf0 = *(const short8*)&Kt[cur][row * 64 + ((lg) ^ (row & 7)) * 8];
      const short8 kf1 = *(const short8*)&Kt[cur][row * 64 + ((4 + lg) ^ (row & 7)) * 8];
#pragma unroll
      for (int qi = 0; qi < 2; qi++) {
        f32x4 z = (f32x4){0.f, 0.f, 0.f, 0.f};
        z = mfma_bf16(qf[qi][0], kf0, z);
        z = mfma_bf16(qf[qi][1], kf1, z);
        s[qi][kj] = z;
      }
    }
    __builtin_amdgcn_s_setprio(0);

    // ---- online softmax (rows q = lg*4+r; cols lr within kj tiles) ----
    float ml[2][4], esc[2][4];
#pragma unroll
    for (int qi = 0; qi < 2; qi++)
#pragma unroll
      for (int r = 0; r < 4; r++) {
        float mx = fmaxf(fmaxf(s[qi][0][r], s[qi][1][r]),
                         fmaxf(s[qi][2][r], s[qi][3][r]));
        mx = fmaxf(mx, __shfl_xor(mx, 1));
        mx = fmaxf(mx, __shfl_xor(mx, 2));
        mx = fmaxf(mx, __shfl_xor(mx, 4));
        mx = fmaxf(mx, __shfl_xor(mx, 8));
        float mn = fmaxf(mrun[qi][r], mx);
        ml[qi][r] = mn;
        esc[qi][r] = __expf((mrun[qi][r] - mn) * 0.125f);
        mrun[qi][r] = mn;
      }
#pragma unroll
    for (int qi = 0; qi < 2; qi++)
#pragma unroll
      for (int kj = 0; kj < 4; kj++)
#pragma unroll
        for (int r = 0; r < 4; r++)
          s[qi][kj][r] = __expf((s[qi][kj][r] - ml[qi][r]) * 0.125f);
#pragma unroll
    for (int qi = 0; qi < 2; qi++)
#pragma unroll
      for (int r = 0; r < 4; r++) {
        float sm = s[qi][0][r] + s[qi][1][r] + s[qi][2][r] + s[qi][3][r];
        sm += __shfl_xor(sm, 1);
        sm += __shfl_xor(sm, 2);
        sm += __shfl_xor(sm, 4);
        sm += __shfl_xor(sm, 8);
        lrun[qi][r] = lrun[qi][r] * esc[qi][r] + sm;
#pragma unroll
        for (int dj = 0; dj < 4; dj++) oacc[qi][dj][r] *= esc[qi][r];
      }

    // ---- write prefetched V into inactive VT buffer (loads have aged) ----
    if (pf) {
#pragma unroll
      for (int e = 0; e < 8; e++) VT[nxt][w * 16 + e][l] = (u16)vr0[e];
#pragma unroll
      for (int e = 0; e < 8; e++) VT[nxt][w * 16 + 8 + e][l] = (u16)vr1[e];
    }

    // ---- P -> per-wave LDS [q][k] ----
#pragma unroll
    for (int qi = 0; qi < 2; qi++)
#pragma unroll
      for (int kj = 0; kj < 4; kj++)
#pragma unroll
        for (int r = 0; r < 4; r++)
          Pl[w][qi * 16 + lg * 4 + r][kj * 16 + lr] = f2bf(s[qi][kj][r]);

    // ---- O += P V from VT[cur] ----
#pragma unroll
    for (int kk = 0; kk < 2; kk++) {
      short8 pa[2], vb[4];
#pragma unroll
      for (int qi = 0; qi < 2; qi++)
        pa[qi] = *(const short8*)&Pl[w][qi * 16 + lr][kk * 32 + lg * 8];
#pragma unroll
      for (int dj = 0; dj < 4; dj++)
        vb[dj] = *(const short8*)&VT[cur][dj * 16 + lr][kk * 32 + lg * 8];
      __builtin_amdgcn_s_setprio(1);
#pragma unroll
      for (int qi = 0; qi < 2; qi++)
#pragma unroll
        for (int dj = 0; dj < 4; dj++)
          oacc[qi][dj] = mfma_bf16(pa[qi], vb[dj], oacc[qi][dj]);
      __builtin_amdgcn_s_setprio(0);
    }
    // single barrier: releases this tile's LDS reads AND (with its implicit
    // vmcnt/lgkm drain) publishes the prefetched Kt[nxt]/VT[nxt] writes.
    __syncthreads();
  }

  // ---- normalize and write AO [b][t][h*64+d] bf16 ----
  const int b = bh >> 4, h = bh & 15;
#pragma unroll
  for (int qi = 0; qi < 2; qi++) {
    float inv[4];
#pragma unroll
    for (int r = 0; r < 4; r++) inv[r] = 1.0f / lrun[qi][r];
#pragma unroll
    for (int dj = 0; dj < 4; dj++)
#pragma unroll
      for (int r = 0; r < 4; r++) {
        int t = q0 + w * 32 + qi * 16 + lg * 4 + r;
        AO[((size_t)(b * 2048 + t)) * 1024 + h * 64 + dj * 16 + lr] =
            f2bf(oacc[qi][dj][r] * inv[r]);
      }
  }
}

extern "C" void kernel_launch(void* const* d_in, const int* in_sizes, int n_in,
                              void* d_out, int out_size, void* d_ws,
                              size_t ws_size, hipStream_t stream) {
  const float* x    = (const float*)d_in[0];  // [4,2048,1024] f32
  const float* Wqkv = (const float*)d_in[1];  // [3072,1024] f32
  const float* bqkv = (const float*)d_in[2];  // [3072] f32
  const float* Wout = (const float*)d_in[3];  // [1024,1024] f32
  const float* bout = (const float*)d_in[4];  // [1024] f32
  float* out = (float*)d_out;                 // [4,2048,1024] f32

  u16* q     = (u16*)d_ws;
  u16* k     = q + (size_t)8388608;
  u16* v     = k + (size_t)8388608;
  u16* xb    = v + (size_t)8388608;
  u16* ao    = xb;  // alias: xb dead after gemm<0>
  u16* wqkvb = xb + (size_t)8388608;
  u16* woutb = wqkvb + (size_t)3145728;

  cvt3<<<12288, 256, 0, stream>>>(x, xb, 8388608, Wqkv, wqkvb, 3145728,
                                  Wout, woutb, 1048576);
  gemm_nt<0><<<dim3(24, 64), 256, 0, stream>>>(xb, wqkvb, bqkv, q, k, v,
                                               nullptr, 3072, 1024);
  attn_fwd<<<dim3(16, 64), 256, 0, stream>>>(q, k, v, ao);
  gemm_nt<1><<<dim3(8, 64), 256, 0, stream>>>(ao, woutb, bout, nullptr, nullptr,
                                              nullptr, out, 1024, 1024);
}

// Round 6
// 236.250 us; speedup vs baseline: 1.4282x; 1.3290x over previous
//
#include <hip/hip_runtime.h>
#include <stdint.h>

typedef unsigned short u16;
typedef unsigned int u32;
typedef __attribute__((ext_vector_type(8))) short short8;
typedef __attribute__((ext_vector_type(4))) float f32x4;
typedef __attribute__((ext_vector_type(4))) u16 u16x4;

#define DEV static __device__ __forceinline__

DEV void gload_lds16(const void* g, void* l) {
  __builtin_amdgcn_global_load_lds((const __attribute__((address_space(1))) void*)g,
                                   (__attribute__((address_space(3))) void*)l, 16, 0, 0);
}
DEV u16 f2bf(float x) {
  u32 u = __builtin_bit_cast(u32, x);
  return (u16)((u + 0x7fffu + ((u >> 16) & 1u)) >> 16);
}
DEV f32x4 mfma_bf16(short8 a, short8 b, f32x4 c) {
  return __builtin_amdgcn_mfma_f32_16x16x32_bf16(a, b, c, 0, 0, 0);
}

// ---------------------------------------------------------------------------
// f32 -> bf16 (RNE) conversion pre-pass over three concatenated arrays.
// ---------------------------------------------------------------------------
__global__ __launch_bounds__(256) void cvt3(
    const float* __restrict__ s0, u16* __restrict__ d0, int n0,
    const float* __restrict__ s1, u16* __restrict__ d1, int n1,
    const float* __restrict__ s2, u16* __restrict__ d2, int n2) {
  long i = (long)(blockIdx.x * 256 + threadIdx.x) * 4;
  const float* s; u16* d; long off;
  if (i < n0) { s = s0; d = d0; off = i; }
  else if (i < (long)n0 + n1) { s = s1; d = d1; off = i - n0; }
  else if (i < (long)n0 + n1 + n2) { s = s2; d = d2; off = i - n0 - n1; }
  else return;
  float4 v = *(const float4*)(s + off);
  u16x4 o; o.x = f2bf(v.x); o.y = f2bf(v.y); o.z = f2bf(v.z); o.w = f2bf(v.w);
  *(u16x4*)(d + off) = o;
}

// ---------------------------------------------------------------------------
// NT GEMM (unchanged from R4-passing): C = A·B^T + bias. M=8192, K=1024.
// ---------------------------------------------------------------------------
template <int MODE>
__global__ __launch_bounds__(256, 2) void gemm_nt(
    const u16* __restrict__ A, const u16* __restrict__ Bw,
    const float* __restrict__ bias, u16* __restrict__ O0, u16* __restrict__ O1,
    u16* __restrict__ O2, float* __restrict__ Of, int N, int K) {
  __shared__ __align__(16) u16 At[128 * 32];
  __shared__ __align__(16) u16 Bt[128 * 32];
  const int tid = threadIdx.x, w = tid >> 6, l = tid & 63;
  const int lr = l & 15, lg = l >> 4;
  const int m0 = blockIdx.y * 128, n0 = blockIdx.x * 128;
  const int wm = w >> 1, wn = w & 1;

  f32x4 acc[4][4];
#pragma unroll
  for (int i = 0; i < 4; i++)
#pragma unroll
    for (int j = 0; j < 4; j++) acc[i][j] = (f32x4){0.f, 0.f, 0.f, 0.f};

  for (int k0 = 0; k0 < K; k0 += 32) {
#pragma unroll
    for (int i = 0; i < 4; i++) {
      int seg = i * 4 + w;          // 0..15 ; <8 -> A, >=8 -> B
      int segl = seg & 7;
      int c = segl * 64 + l;        // 16B chunk 0..511
      int row = c >> 2, cpos = c & 3;
      int cdat = cpos ^ ((row >> 1) & 3);
      const u16* src = (seg < 8 ? A + (size_t)(m0 + row) * K
                                : Bw + (size_t)(n0 + row) * K) + (k0 + cdat * 8);
      u16* dst = (seg < 8 ? At : Bt) + segl * 512;
      gload_lds16(src, dst);
    }
    __syncthreads();

    short8 af[4], bf[4];
#pragma unroll
    for (int mi = 0; mi < 4; mi++) {
      int row = wm * 64 + mi * 16 + lr;
      int cp = lg ^ ((row >> 1) & 3);
      af[mi] = *(const short8*)&At[row * 32 + cp * 8];
    }
#pragma unroll
    for (int ni = 0; ni < 4; ni++) {
      int row = wn * 64 + ni * 16 + lr;
      int cp = lg ^ ((row >> 1) & 3);
      bf[ni] = *(const short8*)&Bt[row * 32 + cp * 8];
    }
#pragma unroll
    for (int mi = 0; mi < 4; mi++)
#pragma unroll
      for (int ni = 0; ni < 4; ni++)
        acc[mi][ni] = mfma_bf16(af[mi], bf[ni], acc[mi][ni]);
    __syncthreads();
  }

#pragma unroll
  for (int ni = 0; ni < 4; ni++) {
    int gn = n0 + wn * 64 + ni * 16 + lr;
    float bs = bias[gn];
#pragma unroll
    for (int mi = 0; mi < 4; mi++) {
#pragma unroll
      for (int r = 0; r < 4; r++) {
        int gm = m0 + wm * 64 + mi * 16 + lg * 4 + r;
        float val = acc[mi][ni][r] + bs;
        if (MODE == 0) {
          int which = gn >> 10, hd = gn & 1023;
          int h = hd >> 6, d = hd & 63;
          int b = gm >> 11, t = gm & 2047;
          u16* dst = which == 0 ? O0 : (which == 1 ? O1 : O2);
          dst[((size_t)(b * 16 + h) * 2048 + t) * 64 + d] = f2bf(val);
        } else {
          Of[(size_t)gm * N + gn] = val;
        }
      }
    }
  }
}

// ---------------------------------------------------------------------------
// Flash attention fwd — R6: swapped QK^T (S^T = mfma(K,Q)) so the k-dim is
// register-resident per lane: row-reduce = 15 in-reg ops + 2 shuffles;
// P-write = 8 x ds_write_b64. Defer-max (T13, THR=64 raw = 8 post-scale)
// makes rescale iterations rare. K/V double-buffered prefetch as R5.
// Frag layouts identical to the R4/R5-passing kernel (A/B symmetric).
// ---------------------------------------------------------------------------
__global__ __launch_bounds__(256, 3) void attn_fwd(
    const u16* __restrict__ Q, const u16* __restrict__ Kg,
    const u16* __restrict__ Vg, u16* __restrict__ AO) {
  __shared__ __align__(16) u16 Kt[2][64 * 64];  // row-major, chunk^(row&7) swizzle
  __shared__ __align__(16) u16 VT[2][64][72];   // V transposed [d][t], +8 pad
  __shared__ __align__(16) u16 Pl[4][32][72];   // per-wave P [q][k], +8 pad
  const int tid = threadIdx.x, w = tid >> 6, l = tid & 63;
  const int lr = l & 15, lg = l >> 4;
  const int bh = blockIdx.y;
  const int q0 = blockIdx.x * 128;
  const size_t base = (size_t)bh * 2048 * 64;
  const u16* Qb = Q + base;
  const u16* Kb = Kg + base;
  const u16* Vb = Vg + base;

  short8 qf[2][2];
#pragma unroll
  for (int qi = 0; qi < 2; qi++)
#pragma unroll
    for (int kk = 0; kk < 2; kk++)
      qf[qi][kk] = *(const short8*)&Qb[(size_t)(q0 + w * 32 + qi * 16 + lr) * 64 +
                                       kk * 32 + lg * 8];

  f32x4 oacc[2][4];
  float mrun[2], lrun[2];
#pragma unroll
  for (int qi = 0; qi < 2; qi++)
#pragma unroll
    for (int dj = 0; dj < 4; dj++) oacc[qi][dj] = (f32x4){0.f, 0.f, 0.f, 0.f};
  mrun[0] = mrun[1] = -3.0e38f;
  lrun[0] = lrun[1] = 0.f;

  // ---- prologue: stage tile 0 into buffer 0 ----
  {
#pragma unroll
    for (int i = 0; i < 2; i++) {
      int seg = i * 4 + w;
      int c = seg * 64 + l;
      int row = c >> 3, cpos = c & 7, cdat = cpos ^ (row & 7);
      gload_lds16(Kb + (size_t)row * 64 + cdat * 8, (u16*)&Kt[0][0] + seg * 512);
    }
    const u16* vsrc = &Vb[(size_t)l * 64 + w * 16];
    short8 v0 = *(const short8*)vsrc;
    short8 v1 = *(const short8*)(vsrc + 8);
#pragma unroll
    for (int e = 0; e < 8; e++) VT[0][w * 16 + e][l] = (u16)v0[e];
#pragma unroll
    for (int e = 0; e < 8; e++) VT[0][w * 16 + 8 + e][l] = (u16)v1[e];
  }
  __syncthreads();

  for (int kt = 0; kt < 32; kt++) {
    const int cur = kt & 1, nxt = cur ^ 1;
    short8 vr0, vr1;
    const bool pf = (kt < 31);
    if (pf) {
      const int t1 = (kt + 1) * 64;
#pragma unroll
      for (int i = 0; i < 2; i++) {
        int seg = i * 4 + w;
        int c = seg * 64 + l;
        int row = c >> 3, cpos = c & 7, cdat = cpos ^ (row & 7);
        gload_lds16(Kb + (size_t)(t1 + row) * 64 + cdat * 8,
                    (u16*)&Kt[nxt][0] + seg * 512);
      }
      const u16* vsrc = &Vb[(size_t)(t1 + l) * 64 + w * 16];
      vr0 = *(const short8*)vsrc;
      vr1 = *(const short8*)(vsrc + 8);
    }

    // ---- S^T = K Q^T from Kt[cur]: st[qi][kj] holds, per lane,
    //      S[q = qi*16+lr][k = kj*16+lg*4+r], r=0..3 ----
    f32x4 st[2][4];
    __builtin_amdgcn_s_setprio(1);
#pragma unroll
    for (int kj = 0; kj < 4; kj++) {
      int row = kj * 16 + lr;
      const short8 kf0 = *(const short8*)&Kt[cur][row * 64 + ((lg) ^ (row & 7)) * 8];
      const short8 kf1 = *(const short8*)&Kt[cur][row * 64 + ((4 + lg) ^ (row & 7)) * 8];
#pragma unroll
      for (int qi = 0; qi < 2; qi++) {
        f32x4 z = (f32x4){0.f, 0.f, 0.f, 0.f};
        z = mfma_bf16(kf0, qf[qi][0], z);
        z = mfma_bf16(kf1, qf[qi][1], z);
        st[qi][kj] = z;
      }
    }
    __builtin_amdgcn_s_setprio(0);

    // ---- tile max per q (in-register over 16 k, then xor16/xor32) ----
    float pm[2];
#pragma unroll
    for (int qi = 0; qi < 2; qi++) {
      f32x4 m4;
#pragma unroll
      for (int r = 0; r < 4; r++)
        m4[r] = fmaxf(fmaxf(st[qi][0][r], st[qi][1][r]),
                      fmaxf(st[qi][2][r], st[qi][3][r]));
      float mx = fmaxf(fmaxf(m4[0], m4[1]), fmaxf(m4[2], m4[3]));
      mx = fmaxf(mx, __shfl_xor(mx, 16));
      mx = fmaxf(mx, __shfl_xor(mx, 32));
      pm[qi] = mx;
    }

    // ---- defer-max: rescale only when max grew by > 64 (raw; 8 post-scale) ----
    float lscale[2] = {1.f, 1.f};
    bool grow = (pm[0] > mrun[0] + 64.f) || (pm[1] > mrun[1] + 64.f);
    if (__any(grow)) {
#pragma unroll
      for (int qi = 0; qi < 2; qi++) {
        float mn = fmaxf(mrun[qi], pm[qi]);
        float e = __expf((mrun[qi] - mn) * 0.125f);
        mrun[qi] = mn;
        lscale[qi] = e;
        float er[4];
#pragma unroll
        for (int r = 0; r < 4; r++)
          er[r] = __shfl(e, (l & 48) | (lg * 4 + r));
#pragma unroll
        for (int dj = 0; dj < 4; dj++)
#pragma unroll
          for (int r = 0; r < 4; r++) oacc[qi][dj][r] *= er[r];
      }
    }

    // ---- P = exp((S - mrun)*scale); row-sum; write P (b64) ----
    float sm[2];
#pragma unroll
    for (int qi = 0; qi < 2; qi++) {
#pragma unroll
      for (int kj = 0; kj < 4; kj++)
#pragma unroll
        for (int r = 0; r < 4; r++)
          st[qi][kj][r] = __expf((st[qi][kj][r] - mrun[qi]) * 0.125f);
      f32x4 s4 = st[qi][0];
#pragma unroll
      for (int kj = 1; kj < 4; kj++)
#pragma unroll
        for (int r = 0; r < 4; r++) s4[r] += st[qi][kj][r];
      float sv = (s4[0] + s4[1]) + (s4[2] + s4[3]);
      sv += __shfl_xor(sv, 16);
      sv += __shfl_xor(sv, 32);
      sm[qi] = sv;
      lrun[qi] = lrun[qi] * lscale[qi] + sv;
#pragma unroll
      for (int kj = 0; kj < 4; kj++) {
        u16x4 pk;
#pragma unroll
        for (int r = 0; r < 4; r++) pk[r] = f2bf(st[qi][kj][r]);
        *(u16x4*)&Pl[w][qi * 16 + lr][kj * 16 + lg * 4] = pk;
      }
    }

    // ---- write prefetched V into inactive VT buffer ----
    if (pf) {
#pragma unroll
      for (int e = 0; e < 8; e++) VT[nxt][w * 16 + e][l] = (u16)vr0[e];
#pragma unroll
      for (int e = 0; e < 8; e++) VT[nxt][w * 16 + 8 + e][l] = (u16)vr1[e];
    }

    // ---- O += P V from VT[cur] (pa reads identical to passing R4/R5) ----
#pragma unroll
    for (int kk = 0; kk < 2; kk++) {
      short8 pa[2], vb[4];
#pragma unroll
      for (int qi = 0; qi < 2; qi++)
        pa[qi] = *(const short8*)&Pl[w][qi * 16 + lr][kk * 32 + lg * 8];
#pragma unroll
      for (int dj = 0; dj < 4; dj++)
        vb[dj] = *(const short8*)&VT[cur][dj * 16 + lr][kk * 32 + lg * 8];
      __builtin_amdgcn_s_setprio(1);
#pragma unroll
      for (int qi = 0; qi < 2; qi++)
#pragma unroll
        for (int dj = 0; dj < 4; dj++)
          oacc[qi][dj] = mfma_bf16(pa[qi], vb[dj], oacc[qi][dj]);
      __builtin_amdgcn_s_setprio(0);
    }
    __syncthreads();
  }

  // ---- normalize (redistribute lrun from q=lr lanes to q=lg*4+r rows) ----
  const int b = bh >> 4, h = bh & 15;
#pragma unroll
  for (int qi = 0; qi < 2; qi++) {
    float inv[4];
#pragma unroll
    for (int r = 0; r < 4; r++) {
      float lv = __shfl(lrun[qi], (l & 48) | (lg * 4 + r));
      inv[r] = 1.0f / lv;
    }
#pragma unroll
    for (int dj = 0; dj < 4; dj++)
#pragma unroll
      for (int r = 0; r < 4; r++) {
        int t = q0 + w * 32 + qi * 16 + lg * 4 + r;
        AO[((size_t)(b * 2048 + t)) * 1024 + h * 64 + dj * 16 + lr] =
            f2bf(oacc[qi][dj][r] * inv[r]);
      }
  }
}

extern "C" void kernel_launch(void* const* d_in, const int* in_sizes, int n_in,
                              void* d_out, int out_size, void* d_ws,
                              size_t ws_size, hipStream_t stream) {
  const float* x    = (const float*)d_in[0];  // [4,2048,1024] f32
  const float* Wqkv = (const float*)d_in[1];  // [3072,1024] f32
  const float* bqkv = (const float*)d_in[2];  // [3072] f32
  const float* Wout = (const float*)d_in[3];  // [1024,1024] f32
  const float* bout = (const float*)d_in[4];  // [1024] f32
  float* out = (float*)d_out;                 // [4,2048,1024] f32

  u16* q     = (u16*)d_ws;
  u16* k     = q + (size_t)8388608;
  u16* v     = k + (size_t)8388608;
  u16* xb    = v + (size_t)8388608;
  u16* ao    = xb;  // alias: xb dead after gemm<0>
  u16* wqkvb = xb + (size_t)8388608;
  u16* woutb = wqkvb + (size_t)3145728;

  cvt3<<<12288, 256, 0, stream>>>(x, xb, 8388608, Wqkv, wqkvb, 3145728,
                                  Wout, woutb, 1048576);
  gemm_nt<0><<<dim3(24, 64), 256, 0, stream>>>(xb, wqkvb, bqkv, q, k, v,
                                               nullptr, 3072, 1024);
  attn_fwd<<<dim3(16, 64), 256, 0, stream>>>(q, k, v, ao);
  gemm_nt<1><<<dim3(8, 64), 256, 0, stream>>>(ao, woutb, bout, nullptr, nullptr,
                                              nullptr, out, 1024, 1024);
}